// Round 1
// 250.876 us; speedup vs baseline: 1.0918x; 1.0918x over previous
//
#include <hip/hip_runtime.h>
#include <math.h>

// Problem constants (fixed by the reference)
constexpr int Bn = 16;    // batch
constexpr int Cn = 256;   // in channels
constexpr int Mn = 128;   // med channels
constexpr int Nn = 4096;  // H*W

typedef short bf16x8 __attribute__((ext_vector_type(8)));     // 8 bf16 (4 VGPRs)
typedef float f32x4 __attribute__((ext_vector_type(4)));      // MFMA accum
typedef unsigned short us8 __attribute__((ext_vector_type(8)));
typedef unsigned short us4 __attribute__((ext_vector_type(4)));

static __device__ __forceinline__ unsigned short f2bf(float f) {
  union { float f; unsigned int u; } c{f};
  unsigned int u = c.u;
  u += 0x7FFFu + ((u >> 16) & 1u);   // RNE
  return (unsigned short)(u >> 16);
}

// ---------------------------------------------------------------------------
// P1: Wst[256][256] bf16 = stack(w_o, w_v) (k-contiguous rows)
// ---------------------------------------------------------------------------
__global__ __launch_bounds__(256) void k_prep_w(
    const float* __restrict__ w_o, const float* __restrict__ w_v,
    unsigned short* __restrict__ Wst) {
  int idx = blockIdx.x * 256 + threadIdx.x;       // over 256*256/4
  int row = idx >> 6;
  int c4 = (idx & 63) * 4;
  const float* src = (row < Mn) ? &w_o[(size_t)row * Cn + c4]
                                : &w_v[(size_t)(row - Mn) * Cn + c4];
  float4 f = *(const float4*)src;
  us4 g = {f2bf(f.x), f2bf(f.y), f2bf(f.z), f2bf(f.w)};
  *(us4*)&Wst[(size_t)row * Cn + c4] = g;
}

// ---------------------------------------------------------------------------
// P2: xT[b][n][c] bf16 = transpose+cast of x[b][c][n].
// ---------------------------------------------------------------------------
__global__ __launch_bounds__(256) void k_prep_x(
    const float* __restrict__ x, unsigned short* __restrict__ xT) {
  const int b = blockIdx.z;
  const int c0 = blockIdx.y * 128;
  const int n0 = blockIdx.x * 64;
  const int t = threadIdx.x;
  const int n4 = (t & 15) * 4;          // 0..60
  const int c8 = c0 + (t >> 4) * 8;     // 8 consecutive c per thread
  const float* xb = x + ((size_t)b * Cn + c8) * Nn + n0 + n4;
  float4 r[8];
#pragma unroll
  for (int i = 0; i < 8; ++i) r[i] = *(const float4*)&xb[(size_t)i * Nn];
  unsigned short* dst = xT + ((size_t)b * Nn + n0 + n4) * Cn + c8;
#pragma unroll
  for (int j = 0; j < 4; ++j) {
    us8 g;
#pragma unroll
    for (int i = 0; i < 8; ++i) g[i] = f2bf(((const float*)&r[i])[j]);
    *(us8*)&dst[(size_t)j * Cn] = g;
  }
}

// ---------------------------------------------------------------------------
// K1 (MFMA): per batch [256x256]@[256x4096] for o and v.
// mt=1 -> v rows: D[m][n] fp32 to v (stats/accA consume this layout).
// mt=0 -> o rows: operand-swapped mfma gives D[n][m] = o^T; written bf16 to
//         oT[b][n][m] (m-contiguous) — the exact B-operand layout k_final
//         needs, at 1/4 the write traffic of fp32 o[m][n].
// ---------------------------------------------------------------------------
__global__ __launch_bounds__(256) void k_proj_mfma(
    const unsigned short* __restrict__ Wst,
    const unsigned short* __restrict__ xT,
    const float* __restrict__ b_o, const float* __restrict__ b_v,
    unsigned short* __restrict__ oT, float* __restrict__ v) {
  __shared__ unsigned short ldsA[8 * 128 * 8];  // [g(8)][row(128)] x 8 bf16
  __shared__ unsigned short ldsB[8 * 128 * 8];
  const int b = blockIdx.z;
  const int mt = blockIdx.y;
  const int nt = blockIdx.x;
  const int t = threadIdx.x;
  const int wave = t >> 6, lane = t & 63;
  const int quad = lane >> 4, l16 = lane & 15;
  const int wm = (wave & 1) * 64, wn = (wave >> 1) * 64;
  f32x4 acc[4][4] = {};
  const unsigned short* Wb = Wst + (size_t)mt * 128 * Cn;
  const unsigned short* xb = xT + ((size_t)b * Nn + nt * 128) * Cn;

  for (int k0 = 0; k0 < Cn; k0 += 64) {
#pragma unroll
    for (int p = 0; p < 4; ++p) {       // 1024 granules per tile, 4/thread
      int s = p * 256 + t;
      int g = s >> 7, row = s & 127;
      *(uint4*)&ldsA[(size_t)s * 8] = *(const uint4*)&Wb[(size_t)row * Cn + k0 + g * 8];
      *(uint4*)&ldsB[(size_t)s * 8] = *(const uint4*)&xb[(size_t)row * Cn + k0 + g * 8];
    }
    __syncthreads();
#pragma unroll
    for (int s = 0; s < 2; ++s) {       // two k-steps of 32
      bf16x8 af[4], bfr[4];
#pragma unroll
      for (int i = 0; i < 4; ++i)
        af[i] = *(const bf16x8*)&ldsA[(size_t)((s * 4 + quad) * 128 + wm + i * 16 + l16) * 8];
#pragma unroll
      for (int j = 0; j < 4; ++j)
        bfr[j] = *(const bf16x8*)&ldsB[(size_t)((s * 4 + quad) * 128 + wn + j * 16 + l16) * 8];
      if (mt) {
#pragma unroll
        for (int i = 0; i < 4; ++i)
#pragma unroll
          for (int j = 0; j < 4; ++j)
            acc[i][j] = __builtin_amdgcn_mfma_f32_16x16x32_bf16(af[i], bfr[j], acc[i][j], 0, 0, 0);
      } else {
        // swapped: D row entity = n (x side), col entity = m (W side)
#pragma unroll
        for (int i = 0; i < 4; ++i)
#pragma unroll
          for (int j = 0; j < 4; ++j)
            acc[i][j] = __builtin_amdgcn_mfma_f32_16x16x32_bf16(bfr[i], af[j], acc[i][j], 0, 0, 0);
      }
    }
    __syncthreads();
  }
  if (mt) {  // v: D[m][n] fp32
    float* dst = v + (size_t)b * Mn * Nn + nt * 128;
#pragma unroll
    for (int i = 0; i < 4; ++i) {
#pragma unroll
      for (int r = 0; r < 4; ++r) {
        int m = wm + i * 16 + quad * 4 + r;
        float bi = b_v[m];
#pragma unroll
        for (int j = 0; j < 4; ++j) {
          int n = wn + j * 16 + l16;
          dst[(size_t)m * Nn + n] = acc[i][j][r] + bi;
        }
      }
    }
  } else {   // o^T: D[n][m] -> bf16 oT[b][n][m]
    float bo_j[4];
#pragma unroll
    for (int j = 0; j < 4; ++j) bo_j[j] = b_o[wm + j * 16 + l16];
#pragma unroll
    for (int i = 0; i < 4; ++i) {
#pragma unroll
      for (int r = 0; r < 4; ++r) {
        int n = nt * 128 + wn + i * 16 + quad * 4 + r;
        unsigned short* row = &oT[((size_t)b * Nn + n) * Mn];
#pragma unroll
        for (int j = 0; j < 4; ++j)
          row[wm + j * 16 + l16] = f2bf(acc[i][j][r] + bo_j[j]);
      }
    }
  }
}

// ---------------------------------------------------------------------------
// K2: row softmax scale per (b,m): rho = exp(-max)/sum = 1/sum_n exp(v[m][n])
// (applied to the Gram matrix in k_reduceA)
// ---------------------------------------------------------------------------
__global__ __launch_bounds__(256) void k_rowstats(
    const float* __restrict__ v, float* __restrict__ rho) {
  const int row = blockIdx.x;  // b*M + m
  const float* vr = v + (size_t)row * Nn;
  const int t = threadIdx.x;
  float vals[16];
  float mx = -1e30f;
#pragma unroll
  for (int p = 0; p < 4; ++p) {
    float4 v4 = *(const float4*)&vr[p * 1024 + t * 4];
    vals[p * 4 + 0] = v4.x; vals[p * 4 + 1] = v4.y;
    vals[p * 4 + 2] = v4.z; vals[p * 4 + 3] = v4.w;
    mx = fmaxf(mx, fmaxf(fmaxf(v4.x, v4.y), fmaxf(v4.z, v4.w)));
  }
  __shared__ float red[256];
  red[t] = mx;
  __syncthreads();
  for (int s = 128; s > 0; s >>= 1) {
    if (t < s) red[t] = fmaxf(red[t], red[t + s]);
    __syncthreads();
  }
  mx = red[0];
  __syncthreads();
  float sum = 0.f;
#pragma unroll
  for (int i = 0; i < 16; ++i) sum += __expf(vals[i] - mx);
  red[t] = sum;
  __syncthreads();
  for (int s = 128; s > 0; s >>= 1) {
    if (t < s) red[t] += red[t + s];
    __syncthreads();
  }
  if (t == 0) rho[row] = __expf(-mx) / red[0];
}

// ---------------------------------------------------------------------------
// K3: column softmax log-offset per (b,n):
//   coff[n] = -0.5*(cm[n] + log(cs[n]))  so  Utilde[n][k] = exp(v[k][n]+coff)
// and Utilde[n][m]*Utilde[n][k] = exp(v[m]-cm)*exp(v[k]-cm)*e^cm/cs exactly
// the softmax-weighted Gram term (symmetric factorization).
// ---------------------------------------------------------------------------
__global__ __launch_bounds__(256) void k_colstats(
    const float* __restrict__ v, float* __restrict__ coff) {
  int idx = blockIdx.x * 256 + threadIdx.x;  // 0..B*N-1
  int b = idx >> 12;
  int n = idx & (Nn - 1);
  const float* vc = v + (size_t)b * Mn * Nn + n;
  float mx = -1e30f;
#pragma unroll 4
  for (int k = 0; k < Mn; ++k) mx = fmaxf(mx, vc[(size_t)k * Nn]);
  float sum = 0.f;
#pragma unroll 4
  for (int k = 0; k < Mn; ++k) sum += __expf(vc[(size_t)k * Nn] - mx);
  coff[idx] = -0.5f * (mx + __logf(sum));
}

// ---------------------------------------------------------------------------
// K4 (MFMA): partial Gram G = Utilde^T Utilde per n-slice.
// Utilde[n][j] = exp(v[j][n] + coff[n]) split into bf16 hi/lo; G accumulated
// as hi*hi + hi*lo + lo*hi (error ~2^-17, lo*lo ~2^-18 dropped) -> fp32-class
// precision on the matrix pipe. LDS slot = g*128 + (row^g): conflict-free
// ds_write_b128 AND conflict-free fragment reads. Next chunk's v is
// prefetched into registers before the MFMA phase (latency hidden).
// ---------------------------------------------------------------------------
__global__ __launch_bounds__(256) void k_accA(
    const float* __restrict__ v, const float* __restrict__ coff,
    float* __restrict__ Ap, int ncols) {
  __shared__ us8 ldsH[8 * 128];  // 16 KB  [g][row^g]
  __shared__ us8 ldsL[8 * 128];  // 16 KB
  const int b = blockIdx.y;
  const int slice = blockIdx.x;
  const int nbase = slice * ncols;
  const int t = threadIdx.x;
  const int wave = t >> 6, lane = t & 63;
  const int quad = lane >> 4, l16 = lane & 15;
  const int wm = (wave & 1) * 64, wk = (wave >> 1) * 64;
  const int rb = t >> 3;        // 0..31 (row base)
  const int g8 = t & 7;         // n-granule of 8
  const float* vb = v + (size_t)b * Mn * Nn;
  const float* cb = coff + (size_t)b * Nn;

  f32x4 acc[4][4] = {};
  float4 pv[4][2];
  float4 pc[2];

  {  // prefetch chunk 0
    int n0 = nbase + g8 * 8;
#pragma unroll
    for (int p = 0; p < 4; ++p) {
      int r = rb + 32 * p;
      pv[p][0] = *(const float4*)&vb[(size_t)r * Nn + n0];
      pv[p][1] = *(const float4*)&vb[(size_t)r * Nn + n0 + 4];
    }
    pc[0] = *(const float4*)&cb[n0];
    pc[1] = *(const float4*)&cb[n0 + 4];
  }

  for (int ch = 0; ch < ncols; ch += 64) {
    // stage: exp + hi/lo bf16 split -> swizzled LDS
#pragma unroll
    for (int p = 0; p < 4; ++p) {
      int r = rb + 32 * p;
      us8 hi8, lo8;
#pragma unroll
      for (int q = 0; q < 8; ++q) {
        float vv = ((const float*)&pv[p][q >> 2])[q & 3];
        float cc = ((const float*)&pc[q >> 2])[q & 3];
        float e = __expf(vv + cc);
        unsigned short h = f2bf(e);
        union { unsigned int u; float f; } hf{(unsigned int)h << 16};
        hi8[q] = h;
        lo8[q] = f2bf(e - hf.f);
      }
      int slot = g8 * 128 + (r ^ g8);
      ldsH[slot] = hi8;
      ldsL[slot] = lo8;
    }
    __syncthreads();
    if (ch + 64 < ncols) {  // prefetch next chunk (hides under MFMA phase)
      int n0 = nbase + ch + 64 + g8 * 8;
#pragma unroll
      for (int p = 0; p < 4; ++p) {
        int r = rb + 32 * p;
        pv[p][0] = *(const float4*)&vb[(size_t)r * Nn + n0];
        pv[p][1] = *(const float4*)&vb[(size_t)r * Nn + n0 + 4];
      }
      pc[0] = *(const float4*)&cb[n0];
      pc[1] = *(const float4*)&cb[n0 + 4];
    }
#pragma unroll
    for (int s = 0; s < 2; ++s) {       // two k-steps of 32 n
      int g = s * 4 + quad;
      bf16x8 hA[4], lA[4], hB[4], lB[4];
#pragma unroll
      for (int i = 0; i < 4; ++i) {
        int mi = wm + i * 16 + l16;
        int ki = wk + i * 16 + l16;
        hA[i] = *(const bf16x8*)&ldsH[g * 128 + (mi ^ g)];
        lA[i] = *(const bf16x8*)&ldsL[g * 128 + (mi ^ g)];
        hB[i] = *(const bf16x8*)&ldsH[g * 128 + (ki ^ g)];
        lB[i] = *(const bf16x8*)&ldsL[g * 128 + (ki ^ g)];
      }
#pragma unroll
      for (int i = 0; i < 4; ++i)
#pragma unroll
        for (int j = 0; j < 4; ++j) {
          acc[i][j] = __builtin_amdgcn_mfma_f32_16x16x32_bf16(hA[i], hB[j], acc[i][j], 0, 0, 0);
          acc[i][j] = __builtin_amdgcn_mfma_f32_16x16x32_bf16(hA[i], lB[j], acc[i][j], 0, 0, 0);
          acc[i][j] = __builtin_amdgcn_mfma_f32_16x16x32_bf16(lA[i], hB[j], acc[i][j], 0, 0, 0);
        }
    }
    __syncthreads();
  }
  float* Apb = Ap + ((size_t)slice * Bn + b) * (Mn * Mn);
#pragma unroll
  for (int i = 0; i < 4; ++i) {
#pragma unroll
    for (int r = 0; r < 4; ++r) {
      int m = wm + i * 16 + quad * 4 + r;
      float* row = &Apb[(size_t)m * Mn];
#pragma unroll
      for (int j = 0; j < 4; ++j)
        row[wk + j * 16 + l16] = acc[i][j][r];
    }
  }
}

// ---------------------------------------------------------------------------
// K4b: A[b][m][k] = rho[b][m] * sum_s Ap[s][b][m][k]
// ---------------------------------------------------------------------------
__global__ __launch_bounds__(256) void k_reduceA(
    const float* __restrict__ Ap, const float* __restrict__ rho,
    float* __restrict__ A, int S) {
  int tid = blockIdx.x * 256 + threadIdx.x;           // over Bn*Mn*Mn/4
  int idx4 = tid * 4;
  int b = idx4 / (Mn * Mn);
  int off = idx4 - b * (Mn * Mn);
  float4 s = {0.f, 0.f, 0.f, 0.f};
  for (int s0 = 0; s0 < S; ++s0) {
    float4 p = *(const float4*)&Ap[((size_t)s0 * Bn + b) * (Mn * Mn) + off];
    s.x += p.x; s.y += p.y; s.z += p.z; s.w += p.w;
  }
  float sc = rho[b * Mn + (off >> 7)];   // row m scale
  s.x *= sc; s.y *= sc; s.z *= sc; s.w *= sc;
  *(float4*)&A[idx4] = s;
}

// ---------------------------------------------------------------------------
// K5: W2bf[b,c,m] = bf16( sum_k w_c[c,k] * A[b,m,k] )  (m-contiguous = the
// A-operand K-layout k_final needs)
// ---------------------------------------------------------------------------
__global__ __launch_bounds__(256) void k_w2(
    const float* __restrict__ w_c, const float* __restrict__ A,
    unsigned short* __restrict__ W2bf) {
  __shared__ float As[64][68];   // [k][m-local]
  __shared__ float wcs[64][68];  // [k][c-local]
  const int b = blockIdx.z;
  const int m0 = blockIdx.x * 64;
  const int c0 = blockIdx.y * 64;
  const int t = threadIdx.x;
  const int tc = (t >> 4) * 4, tmm = (t & 15) * 4;
  float acc[4][4] = {};
  for (int k0 = 0; k0 < Mn; k0 += 64) {
    int r = t >> 2;             // 0..63
    int k4 = (t & 3) * 4;
#pragma unroll
    for (int p = 0; p < 4; ++p) {
      int k = k4 + p * 16;
      float4 a4 = *(const float4*)&A[((size_t)(b * Mn + m0 + r)) * Mn + k0 + k];
      As[k + 0][r] = a4.x; As[k + 1][r] = a4.y; As[k + 2][r] = a4.z; As[k + 3][r] = a4.w;
      float4 w4 = *(const float4*)&w_c[(size_t)(c0 + r) * Mn + k0 + k];
      wcs[k + 0][r] = w4.x; wcs[k + 1][r] = w4.y; wcs[k + 2][r] = w4.z; wcs[k + 3][r] = w4.w;
    }
    __syncthreads();
#pragma unroll
    for (int kk = 0; kk < 64; ++kk) {
      float4 w4 = *(const float4*)&wcs[kk][tc];
      float4 a4 = *(const float4*)&As[kk][tmm];
      float w[4] = {w4.x, w4.y, w4.z, w4.w};
      float a[4] = {a4.x, a4.y, a4.z, a4.w};
#pragma unroll
      for (int i = 0; i < 4; ++i)
#pragma unroll
        for (int jj = 0; jj < 4; ++jj) acc[i][jj] = fmaf(w[i], a[jj], acc[i][jj]);
    }
    __syncthreads();
  }
#pragma unroll
  for (int i = 0; i < 4; ++i) {
    us4 g4 = {f2bf(acc[i][0]), f2bf(acc[i][1]), f2bf(acc[i][2]), f2bf(acc[i][3])};
    *(us4*)&W2bf[((size_t)(b * Cn + c0 + tc + i)) * Mn + m0 + tmm] = g4;
  }
}

// ---------------------------------------------------------------------------
// K6 (MFMA): out[b,c,n] = gamma*relu(sum_m W2bf[c,m]*oT[n,m] + b_c[c]) + x
// Tile 128c x 128n, K=128 fully staged. LDS slot = row*16 + (g ^ (row&15)):
// global reads 256B-coalesced, LDS writes conflict-free, reads 2-way (free).
// ---------------------------------------------------------------------------
__global__ __launch_bounds__(256) void k_final_mfma(
    const unsigned short* __restrict__ W2bf, const unsigned short* __restrict__ oT,
    const float* __restrict__ x, const float* __restrict__ b_c,
    const float* __restrict__ gamma, float* __restrict__ out) {
  __shared__ us8 ldsA[128 * 16];  // 32 KB: [c-row][granule-swizzled]
  __shared__ us8 ldsB[128 * 16];  // 32 KB: [n-row][granule-swizzled]
  const int b = blockIdx.z;
  const int c_t = blockIdx.y * 128;
  const int n_t = blockIdx.x * 128;
  const int t = threadIdx.x;
  const int wave = t >> 6, lane = t & 63;
  const int quad = lane >> 4, l16 = lane & 15;
  const int wc = (wave & 1) * 64, wn = (wave >> 1) * 64;
  const unsigned short* W2b = W2bf + ((size_t)b * Cn + c_t) * Mn;
  const unsigned short* oTb = oT + ((size_t)b * Nn + n_t) * Mn;

#pragma unroll
  for (int p = 0; p < 8; ++p) {   // 2048 granules per operand, 8/thread
    int s = p * 256 + t;
    int row = s >> 4, g = s & 15;
    int slot = row * 16 + (g ^ (row & 15));
    ldsA[slot] = *(const us8*)&W2b[(size_t)row * Mn + g * 8];
    ldsB[slot] = *(const us8*)&oTb[(size_t)row * Mn + g * 8];
  }
  __syncthreads();

  f32x4 acc[4][4] = {};
#pragma unroll
  for (int s = 0; s < 4; ++s) {
    int gq = s * 4 + quad;
    int xo = gq ^ l16;
    bf16x8 af[4], bfr[4];
#pragma unroll
    for (int i = 0; i < 4; ++i)
      af[i] = *(const bf16x8*)&ldsA[(wc + i * 16 + l16) * 16 + xo];
#pragma unroll
    for (int j = 0; j < 4; ++j)
      bfr[j] = *(const bf16x8*)&ldsB[(wn + j * 16 + l16) * 16 + xo];
#pragma unroll
    for (int i = 0; i < 4; ++i)
#pragma unroll
      for (int j = 0; j < 4; ++j)
        acc[i][j] = __builtin_amdgcn_mfma_f32_16x16x32_bf16(af[i], bfr[j], acc[i][j], 0, 0, 0);
  }

  float g = gamma[0];
#pragma unroll
  for (int i = 0; i < 4; ++i) {
#pragma unroll
    for (int r = 0; r < 4; ++r) {
      int c = c_t + wc + i * 16 + quad * 4 + r;
      float bias = b_c[c];
      const float* xr = &x[((size_t)b * Cn + c) * Nn + n_t];
      float* orow = &out[((size_t)b * Cn + c) * Nn + n_t];
#pragma unroll
      for (int j = 0; j < 4; ++j) {
        int n = wn + j * 16 + l16;
        orow[n] = g * fmaxf(acc[i][j][r] + bias, 0.f) + xr[n];
      }
    }
  }
}

// ---------------------------------------------------------------------------
extern "C" void kernel_launch(void* const* d_in, const int* in_sizes, int n_in,
                              void* d_out, int out_size, void* d_ws, size_t ws_size,
                              hipStream_t stream) {
  const float* x   = (const float*)d_in[0];
  const float* w_o = (const float*)d_in[1];
  const float* b_o = (const float*)d_in[2];
  const float* w_v = (const float*)d_in[3];
  const float* b_v = (const float*)d_in[4];
  const float* w_c = (const float*)d_in[5];
  const float* b_c = (const float*)d_in[6];
  const float* gm  = (const float*)d_in[7];

  float* ws = (float*)d_ws;
  float* v    = ws;                               // B*M*N fp32
  float* rho  = v + (size_t)Bn * Mn * Nn;         // B*M
  float* coff = rho + Bn * Mn;                    // B*N
  float* A    = coff + Bn * Nn;                   // B*M*M
  unsigned short* oT   = (unsigned short*)(A + (size_t)Bn * Mn * Mn); // B*N*M bf16
  unsigned short* W2bf = oT + (size_t)Bn * Nn * Mn;                   // B*C*M bf16
  unsigned short* xT   = W2bf + (size_t)Bn * Cn * Mn;                 // B*N*C bf16
  unsigned short* Wst  = xT + (size_t)Bn * Nn * Cn;                   // C*C bf16
  float* Ap = (float*)(Wst + (size_t)Cn * Cn);    // S*B*M*M partials

  size_t base_bytes = (size_t)((char*)Ap - (char*)ws);
  int S = 16;
  if (ws_size < base_bytes + (size_t)16 * Bn * Mn * Mn * sizeof(float)) S = 8;
  const int ncols = Nn / S;

  k_prep_w<<<dim3(Cn * Cn / 1024), 256, 0, stream>>>(w_o, w_v, Wst);
  k_prep_x<<<dim3(Nn / 64, 2, Bn), 256, 0, stream>>>(x, xT);
  k_proj_mfma<<<dim3(Nn / 128, 2, Bn), 256, 0, stream>>>(Wst, xT, b_o, b_v, oT, v);
  k_rowstats<<<dim3(Bn * Mn), 256, 0, stream>>>(v, rho);
  k_colstats<<<dim3(Bn * Nn / 256), 256, 0, stream>>>(v, coff);
  k_accA<<<dim3(S, Bn), 256, 0, stream>>>(v, coff, Ap, ncols);
  k_reduceA<<<dim3(Bn * Mn * Mn / 1024), 256, 0, stream>>>(Ap, rho, A, S);
  k_w2<<<dim3(Mn / 64, Cn / 64, Bn), 256, 0, stream>>>(w_c, A, W2bf);
  k_final_mfma<<<dim3(Nn / 128, Cn / 128, Bn), 256, 0, stream>>>(W2bf, oT, x, b_c, gm, (float*)d_out);
}

// Round 2
// 232.709 us; speedup vs baseline: 1.1771x; 1.0781x over previous
//
#include <hip/hip_runtime.h>
#include <math.h>

// Problem constants (fixed by the reference)
constexpr int Bn = 16;    // batch
constexpr int Cn = 256;   // in channels
constexpr int Mn = 128;   // med channels
constexpr int Nn = 4096;  // H*W

typedef short bf16x8 __attribute__((ext_vector_type(8)));     // 8 bf16 (4 VGPRs)
typedef float f32x4 __attribute__((ext_vector_type(4)));      // MFMA accum
typedef unsigned short us8 __attribute__((ext_vector_type(8)));
typedef unsigned short us4 __attribute__((ext_vector_type(4)));

static __device__ __forceinline__ unsigned short f2bf(float f) {
  union { float f; unsigned int u; } c{f};
  unsigned int u = c.u;
  u += 0x7FFFu + ((u >> 16) & 1u);   // RNE
  return (unsigned short)(u >> 16);
}

// ---------------------------------------------------------------------------
// P1: Wst[256][256] bf16 = stack(w_o, w_v) (k-contiguous rows). Also zeroes
// rs (row-softmax denominators accumulated by atomics in k_proj_mfma).
// ---------------------------------------------------------------------------
__global__ __launch_bounds__(256) void k_prep_w(
    const float* __restrict__ w_o, const float* __restrict__ w_v,
    unsigned short* __restrict__ Wst, float* __restrict__ rs) {
  int idx = blockIdx.x * 256 + threadIdx.x;       // over 256*256/4
  if (idx < Bn * Mn) rs[idx] = 0.f;               // first 8 blocks zero rs
  int row = idx >> 6;
  int c4 = (idx & 63) * 4;
  const float* src = (row < Mn) ? &w_o[(size_t)row * Cn + c4]
                                : &w_v[(size_t)(row - Mn) * Cn + c4];
  float4 f = *(const float4*)src;
  us4 g = {f2bf(f.x), f2bf(f.y), f2bf(f.z), f2bf(f.w)};
  *(us4*)&Wst[(size_t)row * Cn + c4] = g;
}

// ---------------------------------------------------------------------------
// P2: xT[b][n][c] bf16 = transpose+cast of x[b][c][n].
// ---------------------------------------------------------------------------
__global__ __launch_bounds__(256) void k_prep_x(
    const float* __restrict__ x, unsigned short* __restrict__ xT) {
  const int b = blockIdx.z;
  const int c0 = blockIdx.y * 128;
  const int n0 = blockIdx.x * 64;
  const int t = threadIdx.x;
  const int n4 = (t & 15) * 4;          // 0..60
  const int c8 = c0 + (t >> 4) * 8;     // 8 consecutive c per thread
  const float* xb = x + ((size_t)b * Cn + c8) * Nn + n0 + n4;
  float4 r[8];
#pragma unroll
  for (int i = 0; i < 8; ++i) r[i] = *(const float4*)&xb[(size_t)i * Nn];
  unsigned short* dst = xT + ((size_t)b * Nn + n0 + n4) * Cn + c8;
#pragma unroll
  for (int j = 0; j < 4; ++j) {
    us8 g;
#pragma unroll
    for (int i = 0; i < 8; ++i) g[i] = f2bf(((const float*)&r[i])[j]);
    *(us8*)&dst[(size_t)j * Cn] = g;
  }
}

// ---------------------------------------------------------------------------
// K1 (MFMA): per batch [256x256]@[256x4096] projection.
// mt=0 -> o rows: operand-swapped mfma gives D[n][m] = o^T, written bf16 to
//         oT[b][n][m] (the exact B-operand layout k_final needs).
// mt=1 -> v rows: v-tile stays in REGISTERS. Max-free softmax stats:
//         cs[n] = sum_m exp(v) is block-local (block covers all 128 m);
//         rs[m] partials atomicAdd'd. Then Utilde = exp(v)*rsqrt(cs) is
//         hi/lo-bf16 staged to LDS (XOR-granule layout) and the symmetric
//         Gram partial G = U^T U for this n-tile is computed on the matrix
//         pipe (hi*hi + hi*lo + lo*hi) and written to Ap[nt].
//         v is NEVER materialized to global memory.
// ---------------------------------------------------------------------------
__global__ __launch_bounds__(256) void k_proj_mfma(
    const unsigned short* __restrict__ Wst,
    const unsigned short* __restrict__ xT,
    const float* __restrict__ b_o, const float* __restrict__ b_v,
    unsigned short* __restrict__ oT, float* __restrict__ Ap,
    float* __restrict__ rs) {
  __shared__ us8 pool[16 * 128 * 2];   // 64 KB: staging (32 KB) / Gram hi+lo
  __shared__ float cs_lds[4][128];     // per-wave column-sum partials
  unsigned short* ldsA = (unsigned short*)pool;            // 16 KB
  unsigned short* ldsB = (unsigned short*)pool + 8 * 128 * 8;
  const int b = blockIdx.z;
  const int mt = blockIdx.y;
  const int nt = blockIdx.x;
  const int t = threadIdx.x;
  const int wave = t >> 6, lane = t & 63;
  const int quad = lane >> 4, l16 = lane & 15;
  const int wm = (wave & 1) * 64, wn = (wave >> 1) * 64;
  f32x4 acc[4][4] = {};
  const unsigned short* Wb = Wst + (size_t)mt * 128 * Cn;
  const unsigned short* xb = xT + ((size_t)b * Nn + nt * 128) * Cn;

  for (int k0 = 0; k0 < Cn; k0 += 64) {
#pragma unroll
    for (int p = 0; p < 4; ++p) {       // 1024 granules per tile, 4/thread
      int s = p * 256 + t;
      int g = s >> 7, row = s & 127;
      *(uint4*)&ldsA[(size_t)s * 8] = *(const uint4*)&Wb[(size_t)row * Cn + k0 + g * 8];
      *(uint4*)&ldsB[(size_t)s * 8] = *(const uint4*)&xb[(size_t)row * Cn + k0 + g * 8];
    }
    __syncthreads();
#pragma unroll
    for (int s = 0; s < 2; ++s) {       // two k-steps of 32
      bf16x8 af[4], bfr[4];
#pragma unroll
      for (int i = 0; i < 4; ++i)
        af[i] = *(const bf16x8*)&ldsA[(size_t)((s * 4 + quad) * 128 + wm + i * 16 + l16) * 8];
#pragma unroll
      for (int j = 0; j < 4; ++j)
        bfr[j] = *(const bf16x8*)&ldsB[(size_t)((s * 4 + quad) * 128 + wn + j * 16 + l16) * 8];
      if (mt) {
#pragma unroll
        for (int i = 0; i < 4; ++i)
#pragma unroll
          for (int j = 0; j < 4; ++j)
            acc[i][j] = __builtin_amdgcn_mfma_f32_16x16x32_bf16(af[i], bfr[j], acc[i][j], 0, 0, 0);
      } else {
        // swapped: D row entity = n (x side), col entity = m (W side)
#pragma unroll
        for (int i = 0; i < 4; ++i)
#pragma unroll
          for (int j = 0; j < 4; ++j)
            acc[i][j] = __builtin_amdgcn_mfma_f32_16x16x32_bf16(bfr[i], af[j], acc[i][j], 0, 0, 0);
      }
    }
    __syncthreads();
  }

  if (!mt) {   // o^T: D[n][m] -> bf16 oT[b][n][m]
    float bo_j[4];
#pragma unroll
    for (int j = 0; j < 4; ++j) bo_j[j] = b_o[wm + j * 16 + l16];
#pragma unroll
    for (int i = 0; i < 4; ++i) {
#pragma unroll
      for (int r = 0; r < 4; ++r) {
        int n = nt * 128 + wn + i * 16 + quad * 4 + r;
        unsigned short* row = &oT[((size_t)b * Nn + n) * Mn];
#pragma unroll
        for (int j = 0; j < 4; ++j)
          row[wm + j * 16 + l16] = f2bf(acc[i][j][r] + bo_j[j]);
      }
    }
    return;
  }

  // ---- mt=1: v[m][n] tile in acc. e = exp(v + b_v) in place. ----
#pragma unroll
  for (int i = 0; i < 4; ++i) {
#pragma unroll
    for (int r = 0; r < 4; ++r) {
      float bi = b_v[wm + i * 16 + quad * 4 + r];
#pragma unroll
      for (int j = 0; j < 4; ++j)
        acc[i][j][r] = __expf(acc[i][j][r] + bi);
    }
  }

  // Row-sum partials (over this block's 128 n) -> atomicAdd rs[b,m]
#pragma unroll
  for (int i = 0; i < 4; ++i) {
#pragma unroll
    for (int r = 0; r < 4; ++r) {
      float s = acc[i][0][r] + acc[i][1][r] + acc[i][2][r] + acc[i][3][r];
      s += __shfl_xor(s, 1); s += __shfl_xor(s, 2);
      s += __shfl_xor(s, 4); s += __shfl_xor(s, 8);
      if (l16 == 0)
        atomicAdd(&rs[b * Mn + wm + i * 16 + quad * 4 + r], s);
    }
  }

  // Column sums cs[n] over ALL 128 m (block-local): in-lane + cross-quad
  // shfl gives this wave's 64-m partial; LDS combines the two wm halves.
  float csj[4];
#pragma unroll
  for (int j = 0; j < 4; ++j) {
    float c = 0.f;
#pragma unroll
    for (int i = 0; i < 4; ++i)
#pragma unroll
      for (int r = 0; r < 4; ++r) c += acc[i][j][r];
    c += __shfl_xor(c, 16);
    c += __shfl_xor(c, 32);
    csj[j] = c;
  }
  if (quad == 0) {
#pragma unroll
    for (int j = 0; j < 4; ++j) cs_lds[wave][wn + j * 16 + l16] = csj[j];
  }
  __syncthreads();   // also: staging LDS reads done -> safe to overwrite pool

  const int cbase = (wave >> 1) * 2;   // waves {0,1} own n<64; {2,3} own n>=64
  float rinv[4];
#pragma unroll
  for (int j = 0; j < 4; ++j) {
    int nl = wn + j * 16 + l16;
    rinv[j] = rsqrtf(cs_lds[cbase][nl] + cs_lds[cbase + 1][nl]);
  }

  // Stage Utilde hi/lo into XOR-granule LDS: granule g = n/8 (16 of them),
  // slot = g*128 + (m^g), halfword = n&7.
  unsigned short* Hs = (unsigned short*)pool;            // 32 KB (16*128 us8)
  unsigned short* Ls = Hs + 16 * 128 * 8;                // 32 KB
#pragma unroll
  for (int i = 0; i < 4; ++i) {
#pragma unroll
    for (int r = 0; r < 4; ++r) {
      int m = wm + i * 16 + quad * 4 + r;
#pragma unroll
      for (int j = 0; j < 4; ++j) {
        int nl = wn + j * 16 + l16;
        float u = acc[i][j][r] * rinv[j];
        unsigned short h = f2bf(u);
        union { unsigned int q; float f; } hf{(unsigned int)h << 16};
        int idx = ((nl >> 3) * 128 + (m ^ (nl >> 3))) * 8 + (nl & 7);
        Hs[idx] = h;
        Ls[idx] = f2bf(u - hf.f);
      }
    }
  }
  __syncthreads();

  // Gram MFMA: G[m][k] += sum_n U[n][m]*U[n][k], hi/lo 3-product scheme.
  const bf16x8* Hv = (const bf16x8*)pool;
  const bf16x8* Lv = Hv + 16 * 128;
#pragma unroll
  for (int i = 0; i < 4; ++i)
#pragma unroll
    for (int j = 0; j < 4; ++j) acc[i][j] = (f32x4){0.f, 0.f, 0.f, 0.f};
#pragma unroll
  for (int s = 0; s < 4; ++s) {
    int g = s * 4 + quad;
    bf16x8 hA[4], lA[4], hB[4], lB[4];
#pragma unroll
    for (int i = 0; i < 4; ++i) {
      int mi = wm + i * 16 + l16;
      int ki = wn + i * 16 + l16;
      hA[i] = Hv[g * 128 + (mi ^ g)];
      lA[i] = Lv[g * 128 + (mi ^ g)];
      hB[i] = Hv[g * 128 + (ki ^ g)];
      lB[i] = Lv[g * 128 + (ki ^ g)];
    }
#pragma unroll
    for (int i = 0; i < 4; ++i)
#pragma unroll
      for (int j = 0; j < 4; ++j) {
        acc[i][j] = __builtin_amdgcn_mfma_f32_16x16x32_bf16(hA[i], hB[j], acc[i][j], 0, 0, 0);
        acc[i][j] = __builtin_amdgcn_mfma_f32_16x16x32_bf16(hA[i], lB[j], acc[i][j], 0, 0, 0);
        acc[i][j] = __builtin_amdgcn_mfma_f32_16x16x32_bf16(lA[i], hB[j], acc[i][j], 0, 0, 0);
      }
  }

  float* Apb = Ap + ((size_t)nt * Bn + b) * (Mn * Mn);
#pragma unroll
  for (int i = 0; i < 4; ++i) {
#pragma unroll
    for (int r = 0; r < 4; ++r) {
      int m = wm + i * 16 + quad * 4 + r;
      float* row = &Apb[(size_t)m * Mn];
#pragma unroll
      for (int j = 0; j < 4; ++j)
        row[wn + j * 16 + l16] = acc[i][j][r];
    }
  }
}

// ---------------------------------------------------------------------------
// K4b: A[b][m][k] = (1/rs[b][m]) * sum_s Ap[s][b][m][k]
// ---------------------------------------------------------------------------
__global__ __launch_bounds__(256) void k_reduceA(
    const float* __restrict__ Ap, const float* __restrict__ rs,
    float* __restrict__ A, int S) {
  int tid = blockIdx.x * 256 + threadIdx.x;           // over Bn*Mn*Mn/4
  int idx4 = tid * 4;
  int b = idx4 / (Mn * Mn);
  int off = idx4 - b * (Mn * Mn);
  float4 s = {0.f, 0.f, 0.f, 0.f};
  for (int s0 = 0; s0 < S; ++s0) {
    float4 p = *(const float4*)&Ap[((size_t)s0 * Bn + b) * (Mn * Mn) + off];
    s.x += p.x; s.y += p.y; s.z += p.z; s.w += p.w;
  }
  float sc = 1.0f / rs[b * Mn + (off >> 7)];   // row m scale
  s.x *= sc; s.y *= sc; s.z *= sc; s.w *= sc;
  *(float4*)&A[idx4] = s;
}

// ---------------------------------------------------------------------------
// K5: W2bf[b,c,m] = bf16( sum_k w_c[c,k] * A[b,m,k] )  (m-contiguous = the
// A-operand K-layout k_final needs)
// ---------------------------------------------------------------------------
__global__ __launch_bounds__(256) void k_w2(
    const float* __restrict__ w_c, const float* __restrict__ A,
    unsigned short* __restrict__ W2bf) {
  __shared__ float As[64][68];   // [k][m-local]
  __shared__ float wcs[64][68];  // [k][c-local]
  const int b = blockIdx.z;
  const int m0 = blockIdx.x * 64;
  const int c0 = blockIdx.y * 64;
  const int t = threadIdx.x;
  const int tc = (t >> 4) * 4, tmm = (t & 15) * 4;
  float acc[4][4] = {};
  for (int k0 = 0; k0 < Mn; k0 += 64) {
    int r = t >> 2;             // 0..63
    int k4 = (t & 3) * 4;
#pragma unroll
    for (int p = 0; p < 4; ++p) {
      int k = k4 + p * 16;
      float4 a4 = *(const float4*)&A[((size_t)(b * Mn + m0 + r)) * Mn + k0 + k];
      As[k + 0][r] = a4.x; As[k + 1][r] = a4.y; As[k + 2][r] = a4.z; As[k + 3][r] = a4.w;
      float4 w4 = *(const float4*)&w_c[(size_t)(c0 + r) * Mn + k0 + k];
      wcs[k + 0][r] = w4.x; wcs[k + 1][r] = w4.y; wcs[k + 2][r] = w4.z; wcs[k + 3][r] = w4.w;
    }
    __syncthreads();
#pragma unroll
    for (int kk = 0; kk < 64; ++kk) {
      float4 w4 = *(const float4*)&wcs[kk][tc];
      float4 a4 = *(const float4*)&As[kk][tmm];
      float w[4] = {w4.x, w4.y, w4.z, w4.w};
      float a[4] = {a4.x, a4.y, a4.z, a4.w};
#pragma unroll
      for (int i = 0; i < 4; ++i)
#pragma unroll
        for (int jj = 0; jj < 4; ++jj) acc[i][jj] = fmaf(w[i], a[jj], acc[i][jj]);
    }
    __syncthreads();
  }
#pragma unroll
  for (int i = 0; i < 4; ++i) {
    us4 g4 = {f2bf(acc[i][0]), f2bf(acc[i][1]), f2bf(acc[i][2]), f2bf(acc[i][3])};
    *(us4*)&W2bf[((size_t)(b * Cn + c0 + tc + i)) * Mn + m0 + tmm] = g4;
  }
}

// ---------------------------------------------------------------------------
// K6 (MFMA): out[b,c,n] = gamma*relu(sum_m W2bf[c,m]*oT[n,m] + b_c[c]) + x
// Tile 128c x 128n, K=128 fully staged. LDS slot = row*16 + (g ^ (row&15)):
// global reads 256B-coalesced, LDS writes conflict-free, reads 2-way (free).
// ---------------------------------------------------------------------------
__global__ __launch_bounds__(256) void k_final_mfma(
    const unsigned short* __restrict__ W2bf, const unsigned short* __restrict__ oT,
    const float* __restrict__ x, const float* __restrict__ b_c,
    const float* __restrict__ gamma, float* __restrict__ out) {
  __shared__ us8 ldsA[128 * 16];  // 32 KB: [c-row][granule-swizzled]
  __shared__ us8 ldsB[128 * 16];  // 32 KB: [n-row][granule-swizzled]
  const int b = blockIdx.z;
  const int c_t = blockIdx.y * 128;
  const int n_t = blockIdx.x * 128;
  const int t = threadIdx.x;
  const int wave = t >> 6, lane = t & 63;
  const int quad = lane >> 4, l16 = lane & 15;
  const int wc = (wave & 1) * 64, wn = (wave >> 1) * 64;
  const unsigned short* W2b = W2bf + ((size_t)b * Cn + c_t) * Mn;
  const unsigned short* oTb = oT + ((size_t)b * Nn + n_t) * Mn;

#pragma unroll
  for (int p = 0; p < 8; ++p) {   // 2048 granules per operand, 8/thread
    int s = p * 256 + t;
    int row = s >> 4, g = s & 15;
    int slot = row * 16 + (g ^ (row & 15));
    ldsA[slot] = *(const us8*)&W2b[(size_t)row * Mn + g * 8];
    ldsB[slot] = *(const us8*)&oTb[(size_t)row * Mn + g * 8];
  }
  __syncthreads();

  f32x4 acc[4][4] = {};
#pragma unroll
  for (int s = 0; s < 4; ++s) {
    int gq = s * 4 + quad;
    int xo = gq ^ l16;
    bf16x8 af[4], bfr[4];
#pragma unroll
    for (int i = 0; i < 4; ++i)
      af[i] = *(const bf16x8*)&ldsA[(wc + i * 16 + l16) * 16 + xo];
#pragma unroll
    for (int j = 0; j < 4; ++j)
      bfr[j] = *(const bf16x8*)&ldsB[(wn + j * 16 + l16) * 16 + xo];
#pragma unroll
    for (int i = 0; i < 4; ++i)
#pragma unroll
      for (int j = 0; j < 4; ++j)
        acc[i][j] = __builtin_amdgcn_mfma_f32_16x16x32_bf16(af[i], bfr[j], acc[i][j], 0, 0, 0);
  }

  float g = gamma[0];
#pragma unroll
  for (int i = 0; i < 4; ++i) {
#pragma unroll
    for (int r = 0; r < 4; ++r) {
      int c = c_t + wc + i * 16 + quad * 4 + r;
      float bias = b_c[c];
      const float* xr = &x[((size_t)b * Cn + c) * Nn + n_t];
      float* orow = &out[((size_t)b * Cn + c) * Nn + n_t];
#pragma unroll
      for (int j = 0; j < 4; ++j) {
        int n = wn + j * 16 + l16;
        orow[n] = g * fmaxf(acc[i][j][r] + bias, 0.f) + xr[n];
      }
    }
  }
}

// ---------------------------------------------------------------------------
extern "C" void kernel_launch(void* const* d_in, const int* in_sizes, int n_in,
                              void* d_out, int out_size, void* d_ws, size_t ws_size,
                              hipStream_t stream) {
  const float* x   = (const float*)d_in[0];
  const float* w_o = (const float*)d_in[1];
  const float* b_o = (const float*)d_in[2];
  const float* w_v = (const float*)d_in[3];
  const float* b_v = (const float*)d_in[4];
  const float* w_c = (const float*)d_in[5];
  const float* b_c = (const float*)d_in[6];
  const float* gm  = (const float*)d_in[7];

  constexpr int S = Nn / 128;                     // 32 Gram slices (one per nt)
  float* ws = (float*)d_ws;
  float* rs = ws;                                 // B*M
  float* A  = rs + Bn * Mn;                       // B*M*M
  float* Ap = A + (size_t)Bn * Mn * Mn;           // S*B*M*M partials
  unsigned short* oT   = (unsigned short*)(Ap + (size_t)S * Bn * Mn * Mn); // B*N*M bf16
  unsigned short* W2bf = oT + (size_t)Bn * Nn * Mn;                   // B*C*M bf16
  unsigned short* xT   = W2bf + (size_t)Bn * Cn * Mn;                 // B*N*C bf16
  unsigned short* Wst  = xT + (size_t)Bn * Nn * Cn;                   // C*C bf16

  k_prep_w<<<dim3(Cn * Cn / 1024), 256, 0, stream>>>(w_o, w_v, Wst, rs);
  k_prep_x<<<dim3(Nn / 64, 2, Bn), 256, 0, stream>>>(x, xT);
  k_proj_mfma<<<dim3(Nn / 128, 2, Bn), 256, 0, stream>>>(Wst, xT, b_o, b_v, oT, Ap, rs);
  k_reduceA<<<dim3(Bn * Mn * Mn / 1024), 256, 0, stream>>>(Ap, rs, A, S);
  k_w2<<<dim3(Mn / 64, Cn / 64, Bn), 256, 0, stream>>>(w_c, A, W2bf);
  k_final_mfma<<<dim3(Nn / 128, Cn / 128, Bn), 256, 0, stream>>>(W2bf, oT, x, b_c, gm, (float*)d_out);
}